// Round 10
// baseline (212.584 us; speedup 1.0000x reference)
//
#include <hip/hip_runtime.h>
#include <math.h>

#define QN   16384
#define CCH  256
#define NCAM 6
#define HFD  32
#define WFD  88
#define DDD  64
#define BEVH 128
#define BEVW 128
#define IMGW 704.0f
#define IMGH 256.0f
#define EPSV 1e-5f

typedef __attribute__((ext_vector_type(8))) short bf8_t;    // 8 bf16 (MFMA operand)
typedef __attribute__((ext_vector_type(8))) unsigned short us8;
typedef __attribute__((ext_vector_type(4))) unsigned short us4;
typedef __attribute__((ext_vector_type(4))) float f4_t;

__device__ __forceinline__ float sigmoidf_(float x){ return 1.0f/(1.0f+__expf(-x)); }

__device__ __forceinline__ unsigned short f2bf(float f){
    unsigned int b = __float_as_uint(f);
    b += 0x7FFFu + ((b >> 16) & 1u);
    return (unsigned short)(b >> 16);
}
__device__ __forceinline__ float bf2f(unsigned short u){
    return __uint_as_float(((unsigned int)u) << 16);
}

// direct global->LDS DMA, 16B per lane; LDS dest is wave-uniform base + lane*16
#define GLD16(gp_, lp_) __builtin_amdgcn_global_load_lds( \
    (const __attribute__((address_space(1))) unsigned int*)(gp_), \
    (__attribute__((address_space(3))) unsigned int*)(lp_), 16, 0, 0)

// ================= k_prep: proj (0-255) + feat transpose (256-4479) + wtH pack (4480-4735)
//                   + se_w^T (4736-4799) =================
// R10: proj regains COALESCED Aq staging (R7's merge had dropped it -> each lane read
// bq/bpos at stride 1KB = 16-way transaction split on 33.6MB). Weight buffer stored
// as bf16 at stage time (same f2bf -> bit-identical) to shrink LDS: wbf 10.0KB +
// Aq 33.8KB + (sl|tile union) 5.1KB = 48.9KB -> 3 blocks/CU all branches.
__global__ __launch_bounds__(256) void k_prep(const float* __restrict__ feat, unsigned short* __restrict__ feat_tH,
                                              const float* __restrict__ cw, unsigned short* __restrict__ wtH,
                                              const float* __restrict__ se_w, float* __restrict__ se_wT,
                                              float* __restrict__ ssum,
                                              const float* __restrict__ bq, const float* __restrict__ bpos,
                                              const float* __restrict__ refp,
                                              const float* __restrict__ w_pos, const float* __restrict__ b_pos,
                                              const float* __restrict__ w_img, const float* __restrict__ w_att,
                                              float* __restrict__ Sg, float* __restrict__ out_rp){
    __shared__ unsigned short wbf[19][264];     // proj: bf16 weights [j][c]
    __shared__ unsigned short Aq[64][264];      // proj: bf16 q rows, +8 pad
    __shared__ __align__(16) char smu[5120];    // union: sl[64][20] f32 | tile[32][33] f32
    float (*sl)[20]   = (float (*)[20])smu;
    float (*tile)[33] = (float (*)[33])smu;
    int b = blockIdx.x;
    int tid = threadIdx.x;

    if (b < 256){
        // ================= proj =================
        int lane = tid & 63, wid = tid >> 6;
        int l15 = lane & 15, quad = lane >> 4;
        int q0 = b * 64;

        // ---- stage W as bf16 (f32 coalesced reads, f2bf once) ----
        wbf[0][tid] = f2bf(w_pos[tid]);
        #pragma unroll
        for (int r = 0; r < 6; r++){
            int idx = r*256 + tid;
            int c = idx / 6, j = idx - 6*c;
            wbf[1 + j][c] = f2bf(w_att[idx]);
        }
        #pragma unroll
        for (int r = 0; r < 12; r++){
            int idx = r*256 + tid;
            int c = idx / 12, j = idx - 12*c;
            wbf[7 + j][c] = f2bf(w_img[idx]);
        }
        // ---- stage Q = bq + bpos (bf16), block-cooperative, COALESCED ----
        #pragma unroll
        for (int r = 0; r < 16; r++){
            int row = r*4 + wid;
            int cc  = lane * 4;
            float4 a = *(const float4*)(bq   + (size_t)(q0+row)*CCH + cc);
            float4 p = *(const float4*)(bpos + (size_t)(q0+row)*CCH + cc);
            us4 o;
            o.x = f2bf(a.x+p.x); o.y = f2bf(a.y+p.y); o.z = f2bf(a.z+p.z); o.w = f2bf(a.w+p.w);
            *(us4*)&Aq[row][cc] = o;
        }
        __syncthreads();

        f4_t acc0 = (f4_t){0.f,0.f,0.f,0.f};
        f4_t acc1 = (f4_t){0.f,0.f,0.f,0.f};
        const bf8_t zf8 = (bf8_t){0,0,0,0,0,0,0,0};
        #pragma unroll
        for (int kc = 0; kc < 8; kc++){
            int cc = kc*32 + quad*8;
            bf8_t af = *(bf8_t*)&Aq[wid*16 + l15][cc];
            bf8_t b0 = *(bf8_t*)&wbf[l15][cc];
            bf8_t b1 = (l15 < 3) ? *(bf8_t*)&wbf[16 + l15][cc] : zf8;
            acc0 = __builtin_amdgcn_mfma_f32_16x16x32_bf16(af, b0, acc0, 0, 0, 0);
            acc1 = __builtin_amdgcn_mfma_f32_16x16x32_bf16(af, b1, acc1, 0, 0, 0);
        }
        // D: col = lane&15 (j), row = quad*4+reg (query within wave's 16)
        #pragma unroll
        for (int r = 0; r < 4; r++){
            int qq = wid*16 + quad*4 + r;
            sl[qq][l15] = acc0[r];
            if (l15 < 3) sl[qq][16 + l15] = acc1[r];
        }
        __syncthreads();

        if (tid < 64){
            int q = q0 + tid;
            float pos_off = sl[tid][0] + b_pos[0];
            float rx = refp[q*3+0], ry = refp[q*3+1], rz = refp[q*3+2];
            float zc_ = fminf(fmaxf(rz, 0.f), 1.f);
            float inv = logf(fmaxf(zc_, EPSV) / fmaxf(1.f - zc_, EPSV));
            float znew = sigmoidf_(inv + pos_off);
            out_rp[q*3+0] = rx; out_rp[q*3+1] = ry; out_rp[q*3+2] = znew;
            sl[tid][19] = znew;
        }
        __syncthreads();

        for (int i = tid; i < 64*20; i += 256)
            Sg[(size_t)q0*20 + i] = ((const float*)sl)[i];
    } else if (b < 4480){
        // ================= feat transpose (store phase vectorized) =================
        int bb = b - 256;
        int n   = bb / 704;          // 88*8 = 704
        int rem = bb - n*704;
        int cb  = (rem / 88) * 32;
        int pb  = (rem % 88) * 32;
        int tx = tid & 31, ty = tid >> 5;
        for (int r = ty; r < 32; r += 8)
            tile[r][tx] = feat[(size_t)(n*256 + cb + r)*2816 + pb + tx];
        __syncthreads();
        {
            int px_ = tid >> 3;          // 0..31 pixel within tile
            int c4_ = (tid & 7) * 4;     // 0..28 channel group
            us4 o;
            o.x = f2bf(tile[c4_    ][px_]);
            o.y = f2bf(tile[c4_ + 1][px_]);
            o.z = f2bf(tile[c4_ + 2][px_]);
            o.w = f2bf(tile[c4_ + 3][px_]);
            *(us4*)&feat_tH[(size_t)(n*2816 + pb + px_)*256 + cb + c4_] = o;
        }
    } else if (b < 4736){
        // ================= wtH pack: one (co,ci) per thread, contiguous 9-float read ======
        int b2 = b - 4480;                  // 0..255 == co
        if (b2 == 0) ssum[tid] = 0.f;
        int co = b2;
        int ci = tid;
        const float* src = cw + ((size_t)co*256 + ci)*9;
        int chunk = ci >> 6, ciin = ci & 63;
        #pragma unroll
        for (int kk = 0; kk < 9; kk++){
            int kh = kk/3, kw = kk - kh*3;
            size_t dst = ((((size_t)(kh*4 + chunk)*3 + kw)*256 + co) << 6) + ciin;
            wtH[dst] = f2bf(src[kk]);
        }
    } else {
        int tb = b - 4736;                  // 0..63
        int rb_ = (tb >> 3) * 32;           // over t (rows of se_w)
        int cb_ = (tb & 7) * 32;            // over k
        int tx = tid & 31, ty = tid >> 5;
        for (int r = ty; r < 32; r += 8)
            tile[r][tx] = se_w[(size_t)(rb_ + r)*256 + cb_ + tx];
        __syncthreads();
        for (int r = ty; r < 32; r += 8)
            se_wT[(size_t)(cb_ + r)*256 + rb_ + tx] = tile[tx][r];
    }
}

// ================= k_geomagg: per-camera geometry + feature aggregation =================
// R9: compaction + zero-pad to x4 + 4-wide batched gather (MLP 4). Unchanged.
__global__ __launch_bounds__(256) void k_geomagg(
    const float* __restrict__ refp, const float* __restrict__ pcr,
    const float* __restrict__ l2i, const float* __restrict__ dpr,
    const float* __restrict__ b_img, const float* __restrict__ b_att,
    const float* __restrict__ Sg, const unsigned short* __restrict__ feat_tH,
    unsigned short* __restrict__ aggH)
{
    __shared__ float sgl[8][20];
    __shared__ int   so_l[192];
    __shared__ float sw_l[192];
    int bid = blockIdx.x;
    int swz = (bid & 7) * 256 + (bid >> 3);   // XCD-contiguous chunks
    int q0 = swz * 8;
    int tid = threadIdx.x;
    int wid = tid >> 6, lane = tid & 63;

    if (tid < 160) ((float*)sgl)[tid] = Sg[(size_t)q0*20 + tid];
    __syncthreads();

    // ---- per-camera geometry: both queries of the wave in parallel ----
    {
        int sub = lane >> 5;        // 0: even query, 1: odd query
        int n   = lane & 31;        // camera
        if (n < NCAM){
            int ql = wid*2 + sub;
            int q  = q0 + ql;
            float att  = sgl[ql][1+n] + b_att[n];
            float offx = (sgl[ql][7+2*n] + b_img[2*n])   / (float)WFD;
            float offy = (sgl[ql][8+2*n] + b_img[2*n+1]) / (float)HFD;
            float znew = sgl[ql][19];
            float rx = refp[q*3+0], ry = refp[q*3+1];
            float lo0=pcr[0], lo1=pcr[1], lo2=pcr[2];
            float hi0=pcr[3], hi1=pcr[4], hi2=pcr[5];
            float px = rx*(hi0-lo0)+lo0, py = ry*(hi1-lo1)+lo1, pz = znew*(hi2-lo2)+lo2;
            const float* M = l2i + n*16;
            float cx = M[0]*px + M[1]*py + M[2]*pz  + M[3];
            float cy = M[4]*px + M[5]*py + M[6]*pz  + M[7];
            float cz = M[8]*px + M[9]*py + M[10]*pz + M[11];
            bool m = cz > EPSV;
            float zdiv = fmaxf(cz, EPSV);
            float u = (cx/zdiv)/IMGW; u = (u - 0.5f)*2.f;
            float v = (cy/zdiv)/IMGH; v = (v - 0.5f)*2.f;
            m = m && (u > -1.f) && (u < 1.f) && (v > -1.f) && (v < 1.f);
            float rdn = (cz/(float)DDD - 0.5f)*2.f;
            m = m && (rdn > -1.f) && (rdn < 1.f);

            int base = ql*24 + n*4;
            float wq = 0.f, xs = 0.f, ys = 0.f;
            if (m){
                float u2 = u + offx, v2 = v + offy;
                xs = (u2 + 1.f)*0.5f*WFD - 0.5f;
                ys = (v2 + 1.f)*0.5f*HFD - 0.5f;
                float zs = (rdn + 1.f)*0.5f*DDD - 0.5f;
                float fx = floorf(xs), fy = floorf(ys), fz = floorf(zs);
                int x0=(int)fx, y0=(int)fy, z0=(int)fz;
                float wx = xs-fx, wy = ys-fy, wz = zs-fz;
                float dp = 0.f;
                const float* vol = dpr + (size_t)n*DDD*HFD*WFD;
                #pragma unroll
                for (int dz=0; dz<2; dz++)
                #pragma unroll
                for (int dy=0; dy<2; dy++)
                #pragma unroll
                for (int dx=0; dx<2; dx++){
                    int ix=x0+dx, iy=y0+dy, iz=z0+dz;
                    if (ix>=0 && ix<WFD && iy>=0 && iy<HFD && iz>=0 && iz<DDD){
                        float ww = (dx?wx:1.f-wx)*(dy?wy:1.f-wy)*(dz?wz:1.f-wz);
                        dp += ww * vol[(size_t)(iz*HFD+iy)*WFD + ix];
                    }
                }
                wq = sigmoidf_(att) * dp;
            }
            if (m && wq != 0.f){
                float fx = floorf(xs), fy = floorf(ys);
                int x0=(int)fx, y0=(int)fy;
                float wx = xs-fx, wy = ys-fy;
                float cwv[4] = {(1.f-wx)*(1.f-wy), wx*(1.f-wy), (1.f-wx)*wy, wx*wy};
                int xi[4] = {x0, x0+1, x0, x0+1};
                int yi[4] = {y0, y0, y0+1, y0+1};
                #pragma unroll
                for (int k=0;k<4;k++){
                    bool ok = (xi[k]>=0 && xi[k]<WFD && yi[k]>=0 && yi[k]<HFD);
                    so_l[base+k] = ok ? ((n*HFD + yi[k])*WFD + xi[k]) : 0;
                    sw_l[base+k] = ok ? wq*cwv[k] : 0.f;
                }
            } else {
                #pragma unroll
                for (int k=0;k<4;k++){ so_l[base+k] = 0; sw_l[base+k] = 0.f; }
            }
        }
    }
    __syncthreads();

    // ---- compact nonzero entries in-place (stable, wave-private) + zero-pad to x4 ----
    int cnt;
    {
        int half = lane >> 5, li = lane & 31;
        int ql = wid*2 + half;
        bool p = false;
        int   so_v = 0;
        float sw_v = 0.f;
        if (li < 24){
            sw_v = sw_l[ql*24 + li];
            so_v = so_l[ql*24 + li];
            p = (sw_v != 0.f);
        }
        unsigned long long m64 = __ballot(p);
        unsigned int hm = (unsigned int)(half ? (m64 >> 32) : m64);
        cnt = __popc(hm);
        int pos = __popc(hm & ((1u << li) - 1u));
        if (p){
            so_l[ql*24 + pos] = so_v;
            sw_l[ql*24 + pos] = sw_v;
        }
        // zero-fill pad slots [cnt, cnt4): untouched by compaction (disjoint), race-free
        int cnt4 = (cnt + 3) & ~3;
        if (li >= cnt && li < cnt4){
            so_l[ql*24 + li] = 0;
            sw_l[ql*24 + li] = 0.f;
        }
    }

    // ---- gather: 4-wide batched loads (MLP 4), lane halves cover the wave's two queries ----
    {
        int half = lane >> 5, li = lane & 31;
        int c8 = li * 8;
        int ql = wid*2 + half;
        int cnt4 = (cnt + 3) & ~3;
        float a[8] = {0.f,0.f,0.f,0.f,0.f,0.f,0.f,0.f};
        for (int k=0;k<cnt4;k+=4){
            float w0 = sw_l[ql*24+k  ], w1 = sw_l[ql*24+k+1];
            float w2 = sw_l[ql*24+k+2], w3 = sw_l[ql*24+k+3];
            us8 v0 = *(const us8*)(feat_tH + (size_t)so_l[ql*24+k  ]*CCH + c8);
            us8 v1 = *(const us8*)(feat_tH + (size_t)so_l[ql*24+k+1]*CCH + c8);
            us8 v2 = *(const us8*)(feat_tH + (size_t)so_l[ql*24+k+2]*CCH + c8);
            us8 v3 = *(const us8*)(feat_tH + (size_t)so_l[ql*24+k+3]*CCH + c8);
            #pragma unroll
            for (int j=0;j<8;j++) a[j] += w0 * bf2f((unsigned short)v0[j]);
            #pragma unroll
            for (int j=0;j<8;j++) a[j] += w1 * bf2f((unsigned short)v1[j]);
            #pragma unroll
            for (int j=0;j<8;j++) a[j] += w2 * bf2f((unsigned short)v2[j]);
            #pragma unroll
            for (int j=0;j<8;j++) a[j] += w3 * bf2f((unsigned short)v3[j]);
        }
        us8 o;
        #pragma unroll
        for (int j=0;j<8;j++) o[j] = f2bf(a[j]);
        *(us8*)(aggH + (size_t)(q0+ql)*CCH + c8) = o;
    }
}

// ================= k_conv2: 3x3 conv + BN + ReLU + SE-sum (R6, unchanged) =================
__global__ __launch_bounds__(256, 2) void k_conv2(const unsigned short* __restrict__ aggH,
    const unsigned short* __restrict__ wtH, const float* __restrict__ conv_b,
    const float* __restrict__ bn_g, const float* __restrict__ bn_b,
    const float* __restrict__ bn_m, const float* __restrict__ bn_v,
    float* __restrict__ xN, float* __restrict__ ssum)
{
    __shared__ unsigned short Abuf[2][128][64];   // [buf][px w][ci64], linear
    __shared__ unsigned short Bbuf[2][3][64][64]; // [buf][kw][co][ci64], linear

    int h   = blockIdx.x;           // BEV row
    int co0 = blockIdx.y * 64;
    int tid  = threadIdx.x;
    int lane = tid & 63, wid = tid >> 6;
    int m_q = (wid & 1) * 64;
    int n_q = (wid >> 1) * 32;
    int l15 = lane & 15, quad = lane >> 4;
    int swB = l15 & 7;              // B read-side row XOR key

    f4_t acc[4][2];
    #pragma unroll
    for (int i=0;i<4;i++)
    #pragma unroll
    for (int j=0;j<2;j++) acc[i][j] = (f4_t){0.f,0.f,0.f,0.f};

    const us8 z8 = (us8){0,0,0,0,0,0,0,0};
    const bf8_t zf = (bf8_t){0,0,0,0,0,0,0,0};

    #define LOADA(s, bq_) { \
        int kh_ = (s) >> 2; \
        int ph_ = h + kh_ - 1; \
        if (ph_ >= 0 && ph_ < BEVH){ \
            _Pragma("unroll") \
            for (int k_=0; k_<4; k_++){ \
                int w_ = (k_*256 + tid) >> 3; \
                int sd_ = tid & 7; \
                const unsigned short* gp_ = aggH + ((size_t)(ph_*BEVW + w_)*CCH + (((s) & 3) << 6)) \
                                            + ((sd_ ^ (w_ & 7)) << 3); \
                unsigned short* lp_ = &Abuf[bq_][k_*32 + wid*8][0]; \
                GLD16(gp_, lp_); \
            } \
        } else { \
            _Pragma("unroll") \
            for (int k_=0; k_<4; k_++){ \
                int w_ = (k_*256 + tid) >> 3; \
                int sd_ = tid & 7; \
                *(us8*)&Abuf[bq_][w_][sd_*8] = z8; \
            } \
        } \
    }

    #define LOADB(s, bq_) { \
        const unsigned short* bp_ = wtH + (size_t)(s)*49152 + (size_t)co0*64; \
        int srcsw_ = (((tid & 7) ^ ((tid >> 3) & 7)) << 3); \
        _Pragma("unroll") \
        for (int kw_=0; kw_<3; kw_++){ \
            _Pragma("unroll") \
            for (int j_=0; j_<2; j_++){ \
                const unsigned short* gp_ = bp_ + kw_*16384 + (size_t)(j_*32 + (tid>>3))*64 + srcsw_; \
                unsigned short* lp_ = &Bbuf[bq_][kw_][j_*32 + wid*8][0]; \
                GLD16(gp_, lp_); \
            } \
        } \
    }

    LOADA(0, 0);
    LOADB(0, 0);
    int buf = 0;

    for (int s=0; s<12; s++){
        __syncthreads();            // drains DMA(s); all waves done reading buf^1
        if (s < 11){
            LOADA(s+1, buf^1);      // in flight under this stage's MFMA phase
            LOADB(s+1, buf^1);
        }
        #pragma unroll
        for (int ks=0; ks<2; ks++){
            #pragma unroll
            for (int kw=0; kw<3; kw++){
                bf8_t af[4], bfr[2];
                #pragma unroll
                for (int i=0;i<4;i++){
                    int aw = m_q + i*16 + l15 + kw - 1;          // -1..128
                    int awc = min(max(aw, 0), 127);
                    int aslot = (((ks<<2)|quad) ^ (awc & 7));
                    af[i] = *(bf8_t*)&Abuf[buf][awc][aslot*8];
                    if (kw==0 && i==0){ if (m_q==0  && l15==0)  af[i] = zf; }
                    if (kw==2 && i==3){ if (m_q==64 && l15==15) af[i] = zf; }
                }
                #pragma unroll
                for (int j=0;j<2;j++){
                    int slot = (((ks<<2) | quad) ^ swB);
                    bfr[j] = *(bf8_t*)&Bbuf[buf][kw][n_q + j*16 + l15][slot*8];
                }
                #pragma unroll
                for (int i=0;i<4;i++)
                #pragma unroll
                for (int j=0;j<2;j++)
                    acc[i][j] = __builtin_amdgcn_mfma_f32_16x16x32_bf16(af[i], bfr[j], acc[i][j], 0, 0, 0);
            }
        }
        buf ^= 1;
    }
    #undef LOADA
    #undef LOADB

    // ---- epilogue: sacc overlays Abuf (all LDS reads done) ----
    __syncthreads();
    float* sacc = (float*)&Abuf[0][0][0];
    if (tid < 64) sacc[tid] = 0.f;
    __syncthreads();

    #pragma unroll
    for (int j=0;j<2;j++){
        int col = n_q + j*16 + l15;
        int co = co0 + col;
        float sc = bn_g[co] * rsqrtf(bn_v[co] + 1e-5f);
        float sh = bn_b[co] - bn_m[co]*sc;
        float cb = conv_b[co];
        float part = 0.f;
        #pragma unroll
        for (int i=0;i<4;i++){
            #pragma unroll
            for (int r=0;r<4;r++){
                int m = m_q + i*16 + quad*4 + r;
                int p = h*BEVW + m;
                float y = fmaxf((acc[i][j][r] + cb)*sc + sh, 0.f);
                xN[(size_t)p*CCH + co] = y;
                part += y;
            }
        }
        atomicAdd(&sacc[col], part);
    }
    __syncthreads();
    if (tid < 64) atomicAdd(&ssum[co0 + tid], sacc[tid]);
}

// ================= k_maps2: SE scale (coalesced via se_wT) + CBAM channel maps =================
__global__ __launch_bounds__(256) void k_maps2(const float* __restrict__ xN,
    const float* __restrict__ ssum, const float* __restrict__ se_wT, const float* __restrict__ se_b,
    float* __restrict__ scale_g, float* __restrict__ amax, float* __restrict__ amean)
{
    __shared__ float smv[256];
    __shared__ float scl[256];
    int t = threadIdx.x;
    smv[t] = ssum[t] * (1.f/16384.f);
    __syncthreads();
    float a0=0.f, a1=0.f, a2=0.f, a3=0.f;
    for (int k=0; k<256; k+=4){
        a0 += smv[k]   * se_wT[(size_t)(k  )*256 + t];
        a1 += smv[k+1] * se_wT[(size_t)(k+1)*256 + t];
        a2 += smv[k+2] * se_wT[(size_t)(k+2)*256 + t];
        a3 += smv[k+3] * se_wT[(size_t)(k+3)*256 + t];
    }
    float sv = sigmoidf_(se_b[t] + ((a0+a1)+(a2+a3)));
    scl[t] = sv;
    if (blockIdx.x == 0) scale_g[t] = sv;
    __syncthreads();

    int wid = t >> 6, lane = t & 63;
    int p0 = blockIdx.x * 64;
    float4 sc = *(const float4*)&scl[lane*4];
    for (int i=0; i<16; i++){
        int p = p0 + i*4 + wid;
        float4 v = *(const float4*)&xN[(size_t)p*CCH + lane*4];
        float a = v.x*sc.x, b = v.y*sc.y, c = v.z*sc.z, d = v.w*sc.w;
        float mx = fmaxf(fmaxf(a,b), fmaxf(c,d));
        float sm = a+b+c+d;
        #pragma unroll
        for (int off=1; off<64; off<<=1){
            mx = fmaxf(mx, __shfl_xor(mx, off, 64));
            sm += __shfl_xor(sm, off, 64);
        }
        if (lane == 0){ amax[p] = mx; amean[p] = sm*(1.f/256.f); }
    }
}

// ================= k_final2: CBAM 7x7 (in-block) + final scaling =================
__global__ __launch_bounds__(256) void k_final2(const float* __restrict__ xN,
    const float* __restrict__ scale_g, const float* __restrict__ amax, const float* __restrict__ amean,
    const float* __restrict__ cw, const float* __restrict__ cb, float* __restrict__ out)
{
    __shared__ float am2[7][128];
    __shared__ float av2[7][128];
    __shared__ float wcb[98];
    __shared__ float scl[256];
    __shared__ float amap_l[64];

    int b = blockIdx.x;
    int h  = b >> 1;
    int w0 = (b & 1) * 64;
    int t = threadIdx.x;

    scl[t] = scale_g[t];
    if (t < 98) wcb[t] = cw[t];
    for (int idx = t; idx < 896; idx += 256){
        int r = idx >> 7, c = idx & 127;
        int ph = h + r - 3;
        bool ok = (ph >= 0 && ph < BEVH);
        am2[r][c] = ok ? amax[ph*BEVW + c] : 0.f;
        av2[r][c] = ok ? amean[ph*BEVW + c] : 0.f;
    }
    __syncthreads();

    if (t < 64){
        int px = w0 + t;
        float acc = cb[0];
        #pragma unroll
        for (int kh=0; kh<7; kh++){
            #pragma unroll
            for (int kw=0; kw<7; kw++){
                int pw = px + kw - 3;
                if (pw >= 0 && pw < BEVW)
                    acc += am2[kh][pw]*wcb[kh*7+kw] + av2[kh][pw]*wcb[49 + kh*7+kw];
            }
        }
        amap_l[t] = sigmoidf_(acc);
    }
    __syncthreads();

    int lane = t & 63, sub = t >> 6;
    int c4 = lane * 4;
    float4 sc = *(const float4*)&scl[c4];
    for (int i=0; i<16; i++){
        int pxl = sub*16 + i;
        int p = h*BEVW + w0 + pxl;
        float am = amap_l[pxl];
        float4 v = *(const float4*)&xN[(size_t)p*CCH + c4];
        float4 o;
        o.x = v.x*sc.x*am; o.y = v.y*sc.y*am; o.z = v.z*sc.z*am; o.w = v.w*sc.w*am;
        *(float4*)&out[(size_t)p*CCH + c4] = o;
    }
}

extern "C" void kernel_launch(void* const* d_in, const int* in_sizes, int n_in,
                              void* d_out, int out_size, void* d_ws, size_t ws_size,
                              hipStream_t stream) {
    const float* feat   = (const float*)d_in[0];
    const float* bq     = (const float*)d_in[1];
    const float* bpos   = (const float*)d_in[2];
    const float* refp   = (const float*)d_in[3];
    const float* pcr    = (const float*)d_in[4];
    const float* l2i    = (const float*)d_in[5];
    const float* dpr    = (const float*)d_in[6];
    const float* w_pos  = (const float*)d_in[7];
    const float* b_pos  = (const float*)d_in[8];
    const float* w_img  = (const float*)d_in[9];
    const float* b_img  = (const float*)d_in[10];
    const float* w_att  = (const float*)d_in[11];
    const float* b_att  = (const float*)d_in[12];
    const float* conv_w = (const float*)d_in[13];
    const float* conv_b = (const float*)d_in[14];
    const float* bn_g   = (const float*)d_in[15];
    const float* bn_b   = (const float*)d_in[16];
    const float* bn_m   = (const float*)d_in[17];
    const float* bn_v   = (const float*)d_in[18];
    const float* se_w   = (const float*)d_in[19];
    const float* se_b   = (const float*)d_in[20];
    const float* cbw    = (const float*)d_in[21];
    const float* cbb    = (const float*)d_in[22];
    float* out = (float*)d_out;

    float* ws = (float*)d_ws;
    size_t o = 0;
    unsigned short* feat_tH = (unsigned short*)(ws + o); o += (size_t)6*2816*128;  // bf16
    unsigned short* wtH  = (unsigned short*)(ws + o); o += (size_t)9*256*128;      // bf16
    unsigned short* aggH = (unsigned short*)(ws + o); o += (size_t)QN*128;         // bf16
    float* xN      = ws + o;  o += (size_t)QN*256;
    float* se_wT   = ws + o;  o += (size_t)256*256;
    float* Sg      = ws + o;  o += (size_t)QN*20;
    float* ssum    = ws + o;  o += 256;
    float* scale_g = ws + o;  o += 256;
    float* amax    = ws + o;  o += QN;
    float* amean   = ws + o;  o += QN;

    k_prep<<<4800, 256, 0, stream>>>(feat, feat_tH, conv_w, wtH, se_w, se_wT, ssum,
                                     bq, bpos, refp, w_pos, b_pos, w_img, w_att,
                                     Sg, out + (size_t)QN*256);
    k_geomagg<<<2048, 256, 0, stream>>>(refp, pcr, l2i, dpr, b_img, b_att,
                                        Sg, feat_tH, aggH);
    k_conv2<<<dim3(128,4), 256, 0, stream>>>(aggH, wtH, conv_b, bn_g, bn_b, bn_m, bn_v, xN, ssum);
    k_maps2<<<256, 256, 0, stream>>>(xN, ssum, se_wT, se_b, scale_g, amax, amean);
    k_final2<<<256, 256, 0, stream>>>(xN, scale_g, amax, amean, cbw, cbb, out);
}

// Round 11
// 204.088 us; speedup vs baseline: 1.0416x; 1.0416x over previous
//
#include <hip/hip_runtime.h>
#include <math.h>

#define QN   16384
#define CCH  256
#define NCAM 6
#define HFD  32
#define WFD  88
#define DDD  64
#define BEVH 128
#define BEVW 128
#define IMGW 704.0f
#define IMGH 256.0f
#define EPSV 1e-5f

typedef __attribute__((ext_vector_type(8))) short bf8_t;    // 8 bf16 (MFMA operand)
typedef __attribute__((ext_vector_type(8))) unsigned short us8;
typedef __attribute__((ext_vector_type(4))) unsigned short us4;
typedef __attribute__((ext_vector_type(4))) float f4_t;

__device__ __forceinline__ float sigmoidf_(float x){ return 1.0f/(1.0f+__expf(-x)); }

__device__ __forceinline__ unsigned short f2bf(float f){
    unsigned int b = __float_as_uint(f);
    b += 0x7FFFu + ((b >> 16) & 1u);
    return (unsigned short)(b >> 16);
}
__device__ __forceinline__ float bf2f(unsigned short u){
    return __uint_as_float(((unsigned int)u) << 16);
}

// direct global->LDS DMA, 16B per lane; LDS dest is wave-uniform base + lane*16
#define GLD16(gp_, lp_) __builtin_amdgcn_global_load_lds( \
    (const __attribute__((address_space(1))) unsigned int*)(gp_), \
    (__attribute__((address_space(3))) unsigned int*)(lp_), 16, 0, 0)

// ================= k_prep: proj (0-255) + feat transpose (256-4479) + wtH pack (4480-4735)
//                   + se_w^T (4736-4799) ================= (R8/R9 version — R10's larger
// LDS footprint regressed the transpose branch's occupancy 5->3 blocks/CU; reverted)
__global__ __launch_bounds__(256) void k_prep(const float* __restrict__ feat, unsigned short* __restrict__ feat_tH,
                                              const float* __restrict__ cw, unsigned short* __restrict__ wtH,
                                              const float* __restrict__ se_w, float* __restrict__ se_wT,
                                              float* __restrict__ ssum,
                                              const float* __restrict__ bq, const float* __restrict__ bpos,
                                              const float* __restrict__ refp,
                                              const float* __restrict__ w_pos, const float* __restrict__ b_pos,
                                              const float* __restrict__ w_img, const float* __restrict__ w_att,
                                              float* __restrict__ Sg, float* __restrict__ out_rp){
    __shared__ float wlf[19][260];          // proj: [j][c], +4 pad
    __shared__ float sl[64][20];            // proj: result staging
    __shared__ float tile[32][33];          // transpose branches
    int b = blockIdx.x;
    int tid = threadIdx.x;

    if (b < 256){
        // ================= proj =================
        int lane = tid & 63, wid = tid >> 6;
        int l15 = lane & 15, quad = lane >> 4;
        int q0 = b * 64;

        // ---- stage W (f32, coalesced) ----
        wlf[0][tid] = w_pos[tid];
        #pragma unroll
        for (int r = 0; r < 6; r++){
            int idx = r*256 + tid;
            int c = idx / 6, j = idx - 6*c;
            wlf[1 + j][c] = w_att[idx];
        }
        #pragma unroll
        for (int r = 0; r < 12; r++){
            int idx = r*256 + tid;
            int c = idx / 12, j = idx - 12*c;
            wlf[7 + j][c] = w_img[idx];
        }
        __syncthreads();

        f4_t acc0 = (f4_t){0.f,0.f,0.f,0.f};
        f4_t acc1 = (f4_t){0.f,0.f,0.f,0.f};
        const float* qrow = bq   + (size_t)(q0 + wid*16 + l15)*CCH;
        const float* prow = bpos + (size_t)(q0 + wid*16 + l15)*CCH;
        #pragma unroll
        for (int kc = 0; kc < 8; kc++){
            int cc = kc*32 + quad*8;
            float4 a0 = *(const float4*)(qrow + cc);
            float4 a1 = *(const float4*)(qrow + cc + 4);
            float4 p0 = *(const float4*)(prow + cc);
            float4 p1 = *(const float4*)(prow + cc + 4);
            bf8_t af;
            af[0]=(short)f2bf(a0.x+p0.x); af[1]=(short)f2bf(a0.y+p0.y);
            af[2]=(short)f2bf(a0.z+p0.z); af[3]=(short)f2bf(a0.w+p0.w);
            af[4]=(short)f2bf(a1.x+p1.x); af[5]=(short)f2bf(a1.y+p1.y);
            af[6]=(short)f2bf(a1.z+p1.z); af[7]=(short)f2bf(a1.w+p1.w);
            bf8_t b0, b1;
            {
                const float* wr = &wlf[l15][cc];
                float4 w0 = *(const float4*)wr;
                float4 w1 = *(const float4*)(wr + 4);
                b0[0]=(short)f2bf(w0.x); b0[1]=(short)f2bf(w0.y); b0[2]=(short)f2bf(w0.z); b0[3]=(short)f2bf(w0.w);
                b0[4]=(short)f2bf(w1.x); b0[5]=(short)f2bf(w1.y); b0[6]=(short)f2bf(w1.z); b0[7]=(short)f2bf(w1.w);
            }
            if (l15 < 3){
                const float* wr = &wlf[16 + l15][cc];
                float4 w0 = *(const float4*)wr;
                float4 w1 = *(const float4*)(wr + 4);
                b1[0]=(short)f2bf(w0.x); b1[1]=(short)f2bf(w0.y); b1[2]=(short)f2bf(w0.z); b1[3]=(short)f2bf(w0.w);
                b1[4]=(short)f2bf(w1.x); b1[5]=(short)f2bf(w1.y); b1[6]=(short)f2bf(w1.z); b1[7]=(short)f2bf(w1.w);
            } else {
                b1 = (bf8_t){0,0,0,0,0,0,0,0};
            }
            acc0 = __builtin_amdgcn_mfma_f32_16x16x32_bf16(af, b0, acc0, 0, 0, 0);
            acc1 = __builtin_amdgcn_mfma_f32_16x16x32_bf16(af, b1, acc1, 0, 0, 0);
        }
        // D: col = lane&15 (j), row = quad*4+reg (query within wave's 16)
        #pragma unroll
        for (int r = 0; r < 4; r++){
            int qq = wid*16 + quad*4 + r;
            sl[qq][l15] = acc0[r];
            if (l15 < 3) sl[qq][16 + l15] = acc1[r];
        }
        __syncthreads();

        if (tid < 64){
            int q = q0 + tid;
            float pos_off = sl[tid][0] + b_pos[0];
            float rx = refp[q*3+0], ry = refp[q*3+1], rz = refp[q*3+2];
            float zc_ = fminf(fmaxf(rz, 0.f), 1.f);
            float inv = logf(fmaxf(zc_, EPSV) / fmaxf(1.f - zc_, EPSV));
            float znew = sigmoidf_(inv + pos_off);
            out_rp[q*3+0] = rx; out_rp[q*3+1] = ry; out_rp[q*3+2] = znew;
            sl[tid][19] = znew;
        }
        __syncthreads();

        for (int i = tid; i < 64*20; i += 256)
            Sg[(size_t)q0*20 + i] = ((const float*)sl)[i];
    } else if (b < 4480){
        // ================= feat transpose (store phase vectorized) =================
        int bb = b - 256;
        int n   = bb / 704;          // 88*8 = 704
        int rem = bb - n*704;
        int cb  = (rem / 88) * 32;
        int pb  = (rem % 88) * 32;
        int tx = tid & 31, ty = tid >> 5;
        for (int r = ty; r < 32; r += 8)
            tile[r][tx] = feat[(size_t)(n*256 + cb + r)*2816 + pb + tx];
        __syncthreads();
        {
            int px_ = tid >> 3;          // 0..31 pixel within tile
            int c4_ = (tid & 7) * 4;     // 0..28 channel group
            us4 o;
            o.x = f2bf(tile[c4_    ][px_]);
            o.y = f2bf(tile[c4_ + 1][px_]);
            o.z = f2bf(tile[c4_ + 2][px_]);
            o.w = f2bf(tile[c4_ + 3][px_]);
            *(us4*)&feat_tH[(size_t)(n*2816 + pb + px_)*256 + cb + c4_] = o;
        }
    } else if (b < 4736){
        // ================= wtH pack: one (co,ci) per thread, contiguous 9-float read ======
        int b2 = b - 4480;                  // 0..255 == co
        if (b2 == 0) ssum[tid] = 0.f;
        int co = b2;
        int ci = tid;
        const float* src = cw + ((size_t)co*256 + ci)*9;
        int chunk = ci >> 6, ciin = ci & 63;
        #pragma unroll
        for (int kk = 0; kk < 9; kk++){
            int kh = kk/3, kw = kk - kh*3;
            size_t dst = ((((size_t)(kh*4 + chunk)*3 + kw)*256 + co) << 6) + ciin;
            wtH[dst] = f2bf(src[kk]);
        }
    } else {
        int tb = b - 4736;                  // 0..63
        int rb_ = (tb >> 3) * 32;           // over t (rows of se_w)
        int cb_ = (tb & 7) * 32;            // over k
        int tx = tid & 31, ty = tid >> 5;
        for (int r = ty; r < 32; r += 8)
            tile[r][tx] = se_w[(size_t)(rb_ + r)*256 + cb_ + tx];
        __syncthreads();
        for (int r = ty; r < 32; r += 8)
            se_wT[(size_t)(cb_ + r)*256 + rb_ + tx] = tile[tx][r];
    }
}

// ================= k_geomagg: per-camera geometry + feature aggregation =================
// R9: gather batched 4-wide (MLP 4) + compaction + zero-pad to x4. Unchanged.
__global__ __launch_bounds__(256) void k_geomagg(
    const float* __restrict__ refp, const float* __restrict__ pcr,
    const float* __restrict__ l2i, const float* __restrict__ dpr,
    const float* __restrict__ b_img, const float* __restrict__ b_att,
    const float* __restrict__ Sg, const unsigned short* __restrict__ feat_tH,
    unsigned short* __restrict__ aggH)
{
    __shared__ float sgl[8][20];
    __shared__ int   so_l[192];
    __shared__ float sw_l[192];
    int bid = blockIdx.x;
    int swz = (bid & 7) * 256 + (bid >> 3);   // XCD-contiguous chunks
    int q0 = swz * 8;
    int tid = threadIdx.x;
    int wid = tid >> 6, lane = tid & 63;

    if (tid < 160) ((float*)sgl)[tid] = Sg[(size_t)q0*20 + tid];
    __syncthreads();

    // ---- per-camera geometry: both queries of the wave in parallel ----
    {
        int sub = lane >> 5;        // 0: even query, 1: odd query
        int n   = lane & 31;        // camera
        if (n < NCAM){
            int ql = wid*2 + sub;
            int q  = q0 + ql;
            float att  = sgl[ql][1+n] + b_att[n];
            float offx = (sgl[ql][7+2*n] + b_img[2*n])   / (float)WFD;
            float offy = (sgl[ql][8+2*n] + b_img[2*n+1]) / (float)HFD;
            float znew = sgl[ql][19];
            float rx = refp[q*3+0], ry = refp[q*3+1];
            float lo0=pcr[0], lo1=pcr[1], lo2=pcr[2];
            float hi0=pcr[3], hi1=pcr[4], hi2=pcr[5];
            float px = rx*(hi0-lo0)+lo0, py = ry*(hi1-lo1)+lo1, pz = znew*(hi2-lo2)+lo2;
            const float* M = l2i + n*16;
            float cx = M[0]*px + M[1]*py + M[2]*pz  + M[3];
            float cy = M[4]*px + M[5]*py + M[6]*pz  + M[7];
            float cz = M[8]*px + M[9]*py + M[10]*pz + M[11];
            bool m = cz > EPSV;
            float zdiv = fmaxf(cz, EPSV);
            float u = (cx/zdiv)/IMGW; u = (u - 0.5f)*2.f;
            float v = (cy/zdiv)/IMGH; v = (v - 0.5f)*2.f;
            m = m && (u > -1.f) && (u < 1.f) && (v > -1.f) && (v < 1.f);
            float rdn = (cz/(float)DDD - 0.5f)*2.f;
            m = m && (rdn > -1.f) && (rdn < 1.f);

            int base = ql*24 + n*4;
            float wq = 0.f, xs = 0.f, ys = 0.f;
            if (m){
                float u2 = u + offx, v2 = v + offy;
                xs = (u2 + 1.f)*0.5f*WFD - 0.5f;
                ys = (v2 + 1.f)*0.5f*HFD - 0.5f;
                float zs = (rdn + 1.f)*0.5f*DDD - 0.5f;
                float fx = floorf(xs), fy = floorf(ys), fz = floorf(zs);
                int x0=(int)fx, y0=(int)fy, z0=(int)fz;
                float wx = xs-fx, wy = ys-fy, wz = zs-fz;
                float dp = 0.f;
                const float* vol = dpr + (size_t)n*DDD*HFD*WFD;
                #pragma unroll
                for (int dz=0; dz<2; dz++)
                #pragma unroll
                for (int dy=0; dy<2; dy++)
                #pragma unroll
                for (int dx=0; dx<2; dx++){
                    int ix=x0+dx, iy=y0+dy, iz=z0+dz;
                    if (ix>=0 && ix<WFD && iy>=0 && iy<HFD && iz>=0 && iz<DDD){
                        float ww = (dx?wx:1.f-wx)*(dy?wy:1.f-wy)*(dz?wz:1.f-wz);
                        dp += ww * vol[(size_t)(iz*HFD+iy)*WFD + ix];
                    }
                }
                wq = sigmoidf_(att) * dp;
            }
            if (m && wq != 0.f){
                float fx = floorf(xs), fy = floorf(ys);
                int x0=(int)fx, y0=(int)fy;
                float wx = xs-fx, wy = ys-fy;
                float cwv[4] = {(1.f-wx)*(1.f-wy), wx*(1.f-wy), (1.f-wx)*wy, wx*wy};
                int xi[4] = {x0, x0+1, x0, x0+1};
                int yi[4] = {y0, y0, y0+1, y0+1};
                #pragma unroll
                for (int k=0;k<4;k++){
                    bool ok = (xi[k]>=0 && xi[k]<WFD && yi[k]>=0 && yi[k]<HFD);
                    so_l[base+k] = ok ? ((n*HFD + yi[k])*WFD + xi[k]) : 0;
                    sw_l[base+k] = ok ? wq*cwv[k] : 0.f;
                }
            } else {
                #pragma unroll
                for (int k=0;k<4;k++){ so_l[base+k] = 0; sw_l[base+k] = 0.f; }
            }
        }
    }
    __syncthreads();

    // ---- compact nonzero entries in-place (stable, wave-private) + zero-pad to x4 ----
    int cnt;
    {
        int half = lane >> 5, li = lane & 31;
        int ql = wid*2 + half;
        bool p = false;
        int   so_v = 0;
        float sw_v = 0.f;
        if (li < 24){
            sw_v = sw_l[ql*24 + li];
            so_v = so_l[ql*24 + li];
            p = (sw_v != 0.f);
        }
        unsigned long long m64 = __ballot(p);
        unsigned int hm = (unsigned int)(half ? (m64 >> 32) : m64);
        cnt = __popc(hm);
        int pos = __popc(hm & ((1u << li) - 1u));
        if (p){
            so_l[ql*24 + pos] = so_v;
            sw_l[ql*24 + pos] = sw_v;
        }
        // zero-fill pad slots [cnt, cnt4): untouched by compaction (disjoint), race-free
        int cnt4 = (cnt + 3) & ~3;
        if (li >= cnt && li < cnt4){
            so_l[ql*24 + li] = 0;
            sw_l[ql*24 + li] = 0.f;
        }
    }

    // ---- gather: 4-wide batched loads (MLP 4), lane halves cover the wave's two queries ----
    {
        int half = lane >> 5, li = lane & 31;
        int c8 = li * 8;
        int ql = wid*2 + half;
        int cnt4 = (cnt + 3) & ~3;
        float a[8] = {0.f,0.f,0.f,0.f,0.f,0.f,0.f,0.f};
        for (int k=0;k<cnt4;k+=4){
            float w0 = sw_l[ql*24+k  ], w1 = sw_l[ql*24+k+1];
            float w2 = sw_l[ql*24+k+2], w3 = sw_l[ql*24+k+3];
            us8 v0 = *(const us8*)(feat_tH + (size_t)so_l[ql*24+k  ]*CCH + c8);
            us8 v1 = *(const us8*)(feat_tH + (size_t)so_l[ql*24+k+1]*CCH + c8);
            us8 v2 = *(const us8*)(feat_tH + (size_t)so_l[ql*24+k+2]*CCH + c8);
            us8 v3 = *(const us8*)(feat_tH + (size_t)so_l[ql*24+k+3]*CCH + c8);
            #pragma unroll
            for (int j=0;j<8;j++) a[j] += w0 * bf2f((unsigned short)v0[j]);
            #pragma unroll
            for (int j=0;j<8;j++) a[j] += w1 * bf2f((unsigned short)v1[j]);
            #pragma unroll
            for (int j=0;j<8;j++) a[j] += w2 * bf2f((unsigned short)v2[j]);
            #pragma unroll
            for (int j=0;j<8;j++) a[j] += w3 * bf2f((unsigned short)v3[j]);
        }
        us8 o;
        #pragma unroll
        for (int j=0;j<8;j++) o[j] = f2bf(a[j]);
        *(us8*)(aggH + (size_t)(q0+ql)*CCH + c8) = o;
    }
}

// ================= k_conv2: 3x3 conv + BN + ReLU + SE-sum (R6, unchanged) =================
__global__ __launch_bounds__(256, 2) void k_conv2(const unsigned short* __restrict__ aggH,
    const unsigned short* __restrict__ wtH, const float* __restrict__ conv_b,
    const float* __restrict__ bn_g, const float* __restrict__ bn_b,
    const float* __restrict__ bn_m, const float* __restrict__ bn_v,
    float* __restrict__ xN, float* __restrict__ ssum)
{
    __shared__ unsigned short Abuf[2][128][64];   // [buf][px w][ci64], linear
    __shared__ unsigned short Bbuf[2][3][64][64]; // [buf][kw][co][ci64], linear

    int h   = blockIdx.x;           // BEV row
    int co0 = blockIdx.y * 64;
    int tid  = threadIdx.x;
    int lane = tid & 63, wid = tid >> 6;
    int m_q = (wid & 1) * 64;
    int n_q = (wid >> 1) * 32;
    int l15 = lane & 15, quad = lane >> 4;
    int swB = l15 & 7;              // B read-side row XOR key

    f4_t acc[4][2];
    #pragma unroll
    for (int i=0;i<4;i++)
    #pragma unroll
    for (int j=0;j<2;j++) acc[i][j] = (f4_t){0.f,0.f,0.f,0.f};

    const us8 z8 = (us8){0,0,0,0,0,0,0,0};
    const bf8_t zf = (bf8_t){0,0,0,0,0,0,0,0};

    #define LOADA(s, bq_) { \
        int kh_ = (s) >> 2; \
        int ph_ = h + kh_ - 1; \
        if (ph_ >= 0 && ph_ < BEVH){ \
            _Pragma("unroll") \
            for (int k_=0; k_<4; k_++){ \
                int w_ = (k_*256 + tid) >> 3; \
                int sd_ = tid & 7; \
                const unsigned short* gp_ = aggH + ((size_t)(ph_*BEVW + w_)*CCH + (((s) & 3) << 6)) \
                                            + ((sd_ ^ (w_ & 7)) << 3); \
                unsigned short* lp_ = &Abuf[bq_][k_*32 + wid*8][0]; \
                GLD16(gp_, lp_); \
            } \
        } else { \
            _Pragma("unroll") \
            for (int k_=0; k_<4; k_++){ \
                int w_ = (k_*256 + tid) >> 3; \
                int sd_ = tid & 7; \
                *(us8*)&Abuf[bq_][w_][sd_*8] = z8; \
            } \
        } \
    }

    #define LOADB(s, bq_) { \
        const unsigned short* bp_ = wtH + (size_t)(s)*49152 + (size_t)co0*64; \
        int srcsw_ = (((tid & 7) ^ ((tid >> 3) & 7)) << 3); \
        _Pragma("unroll") \
        for (int kw_=0; kw_<3; kw_++){ \
            _Pragma("unroll") \
            for (int j_=0; j_<2; j_++){ \
                const unsigned short* gp_ = bp_ + kw_*16384 + (size_t)(j_*32 + (tid>>3))*64 + srcsw_; \
                unsigned short* lp_ = &Bbuf[bq_][kw_][j_*32 + wid*8][0]; \
                GLD16(gp_, lp_); \
            } \
        } \
    }

    LOADA(0, 0);
    LOADB(0, 0);
    int buf = 0;

    for (int s=0; s<12; s++){
        __syncthreads();            // drains DMA(s); all waves done reading buf^1
        if (s < 11){
            LOADA(s+1, buf^1);      // in flight under this stage's MFMA phase
            LOADB(s+1, buf^1);
        }
        #pragma unroll
        for (int ks=0; ks<2; ks++){
            #pragma unroll
            for (int kw=0; kw<3; kw++){
                bf8_t af[4], bfr[2];
                #pragma unroll
                for (int i=0;i<4;i++){
                    int aw = m_q + i*16 + l15 + kw - 1;          // -1..128
                    int awc = min(max(aw, 0), 127);
                    int aslot = (((ks<<2)|quad) ^ (awc & 7));
                    af[i] = *(bf8_t*)&Abuf[buf][awc][aslot*8];
                    if (kw==0 && i==0){ if (m_q==0  && l15==0)  af[i] = zf; }
                    if (kw==2 && i==3){ if (m_q==64 && l15==15) af[i] = zf; }
                }
                #pragma unroll
                for (int j=0;j<2;j++){
                    int slot = (((ks<<2) | quad) ^ swB);
                    bfr[j] = *(bf8_t*)&Bbuf[buf][kw][n_q + j*16 + l15][slot*8];
                }
                #pragma unroll
                for (int i=0;i<4;i++)
                #pragma unroll
                for (int j=0;j<2;j++)
                    acc[i][j] = __builtin_amdgcn_mfma_f32_16x16x32_bf16(af[i], bfr[j], acc[i][j], 0, 0, 0);
            }
        }
        buf ^= 1;
    }
    #undef LOADA
    #undef LOADB

    // ---- epilogue: sacc overlays Abuf (all LDS reads done) ----
    __syncthreads();
    float* sacc = (float*)&Abuf[0][0][0];
    if (tid < 64) sacc[tid] = 0.f;
    __syncthreads();

    #pragma unroll
    for (int j=0;j<2;j++){
        int col = n_q + j*16 + l15;
        int co = co0 + col;
        float sc = bn_g[co] * rsqrtf(bn_v[co] + 1e-5f);
        float sh = bn_b[co] - bn_m[co]*sc;
        float cb = conv_b[co];
        float part = 0.f;
        #pragma unroll
        for (int i=0;i<4;i++){
            #pragma unroll
            for (int r=0;r<4;r++){
                int m = m_q + i*16 + quad*4 + r;
                int p = h*BEVW + m;
                float y = fmaxf((acc[i][j][r] + cb)*sc + sh, 0.f);
                xN[(size_t)p*CCH + co] = y;
                part += y;
            }
        }
        atomicAdd(&sacc[col], part);
    }
    __syncthreads();
    if (tid < 64) atomicAdd(&ssum[co0 + tid], sacc[tid]);
}

// ================= k_maps2: SE scale (coalesced via se_wT) + CBAM channel maps =================
__global__ __launch_bounds__(256) void k_maps2(const float* __restrict__ xN,
    const float* __restrict__ ssum, const float* __restrict__ se_wT, const float* __restrict__ se_b,
    float* __restrict__ scale_g, float* __restrict__ amax, float* __restrict__ amean)
{
    __shared__ float smv[256];
    __shared__ float scl[256];
    int t = threadIdx.x;
    smv[t] = ssum[t] * (1.f/16384.f);
    __syncthreads();
    float a0=0.f, a1=0.f, a2=0.f, a3=0.f;
    for (int k=0; k<256; k+=4){
        a0 += smv[k]   * se_wT[(size_t)(k  )*256 + t];
        a1 += smv[k+1] * se_wT[(size_t)(k+1)*256 + t];
        a2 += smv[k+2] * se_wT[(size_t)(k+2)*256 + t];
        a3 += smv[k+3] * se_wT[(size_t)(k+3)*256 + t];
    }
    float sv = sigmoidf_(se_b[t] + ((a0+a1)+(a2+a3)));
    scl[t] = sv;
    if (blockIdx.x == 0) scale_g[t] = sv;
    __syncthreads();

    int wid = t >> 6, lane = t & 63;
    int p0 = blockIdx.x * 64;
    float4 sc = *(const float4*)&scl[lane*4];
    for (int i=0; i<16; i++){
        int p = p0 + i*4 + wid;
        float4 v = *(const float4*)&xN[(size_t)p*CCH + lane*4];
        float a = v.x*sc.x, b = v.y*sc.y, c = v.z*sc.z, d = v.w*sc.w;
        float mx = fmaxf(fmaxf(a,b), fmaxf(c,d));
        float sm = a+b+c+d;
        #pragma unroll
        for (int off=1; off<64; off<<=1){
            mx = fmaxf(mx, __shfl_xor(mx, off, 64));
            sm += __shfl_xor(sm, off, 64);
        }
        if (lane == 0){ amax[p] = mx; amean[p] = sm*(1.f/256.f); }
    }
}

// ================= k_final2: CBAM 7x7 (in-block) + final scaling =================
__global__ __launch_bounds__(256) void k_final2(const float* __restrict__ xN,
    const float* __restrict__ scale_g, const float* __restrict__ amax, const float* __restrict__ amean,
    const float* __restrict__ cw, const float* __restrict__ cb, float* __restrict__ out)
{
    __shared__ float am2[7][128];
    __shared__ float av2[7][128];
    __shared__ float wcb[98];
    __shared__ float scl[256];
    __shared__ float amap_l[64];

    int b = blockIdx.x;
    int h  = b >> 1;
    int w0 = (b & 1) * 64;
    int t = threadIdx.x;

    scl[t] = scale_g[t];
    if (t < 98) wcb[t] = cw[t];
    for (int idx = t; idx < 896; idx += 256){
        int r = idx >> 7, c = idx & 127;
        int ph = h + r - 3;
        bool ok = (ph >= 0 && ph < BEVH);
        am2[r][c] = ok ? amax[ph*BEVW + c] : 0.f;
        av2[r][c] = ok ? amean[ph*BEVW + c] : 0.f;
    }
    __syncthreads();

    if (t < 64){
        int px = w0 + t;
        float acc = cb[0];
        #pragma unroll
        for (int kh=0; kh<7; kh++){
            #pragma unroll
            for (int kw=0; kw<7; kw++){
                int pw = px + kw - 3;
                if (pw >= 0 && pw < BEVW)
                    acc += am2[kh][pw]*wcb[kh*7+kw] + av2[kh][pw]*wcb[49 + kh*7+kw];
            }
        }
        amap_l[t] = sigmoidf_(acc);
    }
    __syncthreads();

    int lane = t & 63, sub = t >> 6;
    int c4 = lane * 4;
    float4 sc = *(const float4*)&scl[c4];
    for (int i=0; i<16; i++){
        int pxl = sub*16 + i;
        int p = h*BEVW + w0 + pxl;
        float am = amap_l[pxl];
        float4 v = *(const float4*)&xN[(size_t)p*CCH + c4];
        float4 o;
        o.x = v.x*sc.x*am; o.y = v.y*sc.y*am; o.z = v.z*sc.z*am; o.w = v.w*sc.w*am;
        *(float4*)&out[(size_t)p*CCH + c4] = o;
    }
}

extern "C" void kernel_launch(void* const* d_in, const int* in_sizes, int n_in,
                              void* d_out, int out_size, void* d_ws, size_t ws_size,
                              hipStream_t stream) {
    const float* feat   = (const float*)d_in[0];
    const float* bq     = (const float*)d_in[1];
    const float* bpos   = (const float*)d_in[2];
    const float* refp   = (const float*)d_in[3];
    const float* pcr    = (const float*)d_in[4];
    const float* l2i    = (const float*)d_in[5];
    const float* dpr    = (const float*)d_in[6];
    const float* w_pos  = (const float*)d_in[7];
    const float* b_pos  = (const float*)d_in[8];
    const float* w_img  = (const float*)d_in[9];
    const float* b_img  = (const float*)d_in[10];
    const float* w_att  = (const float*)d_in[11];
    const float* b_att  = (const float*)d_in[12];
    const float* conv_w = (const float*)d_in[13];
    const float* conv_b = (const float*)d_in[14];
    const float* bn_g   = (const float*)d_in[15];
    const float* bn_b   = (const float*)d_in[16];
    const float* bn_m   = (const float*)d_in[17];
    const float* bn_v   = (const float*)d_in[18];
    const float* se_w   = (const float*)d_in[19];
    const float* se_b   = (const float*)d_in[20];
    const float* cbw    = (const float*)d_in[21];
    const float* cbb    = (const float*)d_in[22];
    float* out = (float*)d_out;

    float* ws = (float*)d_ws;
    size_t o = 0;
    unsigned short* feat_tH = (unsigned short*)(ws + o); o += (size_t)6*2816*128;  // bf16
    unsigned short* wtH  = (unsigned short*)(ws + o); o += (size_t)9*256*128;      // bf16
    unsigned short* aggH = (unsigned short*)(ws + o); o += (size_t)QN*128;         // bf16
    float* xN      = ws + o;  o += (size_t)QN*256;
    float* se_wT   = ws + o;  o += (size_t)256*256;
    float* Sg      = ws + o;  o += (size_t)QN*20;
    float* ssum    = ws + o;  o += 256;
    float* scale_g = ws + o;  o += 256;
    float* amax    = ws + o;  o += QN;
    float* amean   = ws + o;  o += QN;

    k_prep<<<4800, 256, 0, stream>>>(feat, feat_tH, conv_w, wtH, se_w, se_wT, ssum,
                                     bq, bpos, refp, w_pos, b_pos, w_img, w_att,
                                     Sg, out + (size_t)QN*256);
    k_geomagg<<<2048, 256, 0, stream>>>(refp, pcr, l2i, dpr, b_img, b_att,
                                        Sg, feat_tH, aggH);
    k_conv2<<<dim3(128,4), 256, 0, stream>>>(aggH, wtH, conv_b, bn_g, bn_b, bn_m, bn_v, xN, ssum);
    k_maps2<<<256, 256, 0, stream>>>(xN, ssum, se_wT, se_b, scale_g, amax, amean);
    k_final2<<<256, 256, 0, stream>>>(xN, scale_g, amax, amean, cbw, cbb, out);
}